// Round 1
// baseline (641.929 us; speedup 1.0000x reference)
//
#include <hip/hip_runtime.h>
#include <math.h>

#define BB 2
#define SS 4096
#define HH 16
#define DD 128
#define CHUNK 64
#define NTC (SS / CHUNK)   // 64 chunks
#define KPAD 132           // padded LDS row stride (floats), keeps 16B alignment

// ---------------- Phase 1: per-group sums of K^T V ----------------
// grid (NG, H, B), block 256. Each block sums k^T v over CPG chunks.
__global__ __launch_bounds__(256) void ksum_kernel(const float* __restrict__ k,
                                                   const float* __restrict__ v,
                                                   float* __restrict__ G,
                                                   int CPG, int NG) {
    int g = blockIdx.x, h = blockIdx.y, b = blockIdx.z;
    int t = threadIdx.x;
    __shared__ float lk[CHUNK][KPAD];
    __shared__ float lv[CHUNK][KPAD];
    int d0  = t >> 1;          // owned state row 0..127
    int e4b = (t & 1) * 16;    // owned float4-col base (16 float4 = 64 cols)

    float4 acc[16];
#pragma unroll
    for (int i = 0; i < 16; ++i) acc[i] = make_float4(0.f, 0.f, 0.f, 0.f);

    for (int c = 0; c < CPG; ++c) {
        int chunk = g * CPG + c;
        long base = ((long)b * SS + (long)chunk * CHUNK) * (HH * DD) + (long)h * DD;
        __syncthreads();
        for (int idx = t; idx < CHUNK * (DD / 4); idx += 256) {
            int r = idx >> 5, d4 = idx & 31;
            *(float4*)(&lk[r][4 * d4]) = *(const float4*)(k + base + (long)r * (HH * DD) + 4 * d4);
            *(float4*)(&lv[r][4 * d4]) = *(const float4*)(v + base + (long)r * (HH * DD) + 4 * d4);
        }
        __syncthreads();
        for (int r = 0; r < CHUNK; ++r) {
            float kd = lk[r][d0];
            const float4* vrow = (const float4*)(&lv[r][0]);
#pragma unroll
            for (int i = 0; i < 16; ++i) {
                float4 vv = vrow[e4b + i];
                acc[i].x += kd * vv.x; acc[i].y += kd * vv.y;
                acc[i].z += kd * vv.z; acc[i].w += kd * vv.w;
            }
        }
    }
    long gb = ((long)(b * HH + h) * NG + g) * (DD * DD) + (long)d0 * DD + (long)e4b * 4;
#pragma unroll
    for (int i = 0; i < 16; ++i) *(float4*)(G + gb + 4 * i) = acc[i];
}

// ---------------- Phase 2: exclusive prefix over groups (in-place) ----------------
// grid (8, H, B), block 256. Also writes final_state (total sum).
__global__ __launch_bounds__(256) void prefix_kernel(float* __restrict__ G,
                                                     float* __restrict__ hf,
                                                     int NG) {
    int eb = blockIdx.x * 16;
    int h = blockIdx.y, b = blockIdx.z;
    int t = threadIdx.x;
    int d0 = t >> 1;
    int eo = eb + (t & 1) * 8;
    long bh = (long)(b * HH + h);
    float4 a0 = make_float4(0.f, 0.f, 0.f, 0.f), a1 = a0;
    for (int g = 0; g < NG; ++g) {
        float* p = G + (bh * NG + g) * (DD * DD) + (long)d0 * DD + eo;
        float4 v0 = *(float4*)p;
        float4 v1 = *(float4*)(p + 4);
        *(float4*)p       = a0;
        *(float4*)(p + 4) = a1;
        a0.x += v0.x; a0.y += v0.y; a0.z += v0.z; a0.w += v0.w;
        a1.x += v1.x; a1.y += v1.y; a1.z += v1.z; a1.w += v1.w;
    }
    float* qp = hf + bh * (DD * DD) + (long)d0 * DD + eo;
    *(float4*)qp       = a0;
    *(float4*)(qp + 4) = a1;
}

// ---------------- Phase 3: per-group scan producing o ----------------
// grid (NG, H, B), block 256 (4 waves). LDS: h 64KB + k 33KB + v 33KB = 130KB.
__global__ __launch_bounds__(256, 1) void scan_kernel(const float* __restrict__ q,
                                                      const float* __restrict__ kk,
                                                      const float* __restrict__ vv,
                                                      const float* __restrict__ Hs,
                                                      float* __restrict__ o,
                                                      int CPG, int NG, float scale) {
    int g = blockIdx.x, h = blockIdx.y, b = blockIdx.z;
    int t = threadIdx.x;
    __shared__ float hS[DD][DD];
    __shared__ float lk[CHUNK][KPAD];
    __shared__ float lv[CHUNK][KPAD];

    int lane = t & 63;
    int wave = t >> 6;
    int row  = t >> 2;   // 0..63: output row within chunk
    int p    = t & 3;    // quarter index

    // load group-start state into LDS
    {
        const float* src = Hs + ((long)(b * HH + h) * NG + g) * (DD * DD);
        for (int idx = t; idx < DD * DD / 4; idx += 256)
            *(float4*)(&hS[0][0] + 4 * idx) = *(const float4*)(src + 4 * idx);
    }

    for (int c = 0; c < CPG; ++c) {
        int chunk = g * CPG + c;
        long base = ((long)b * SS + (long)chunk * CHUNK) * (HH * DD) + (long)h * DD;
        __syncthreads();  // prev-iter LDS reads done (and Hstart load on iter 0)
        for (int idx = t; idx < CHUNK * (DD / 4); idx += 256) {
            int r = idx >> 5, d4 = idx & 31;
            *(float4*)(&lk[r][4 * d4]) = *(const float4*)(kk + base + (long)r * (HH * DD) + 4 * d4);
            *(float4*)(&lv[r][4 * d4]) = *(const float4*)(vv + base + (long)r * (HH * DD) + 4 * d4);
        }
        // q row quarter into registers, pre-scaled
        float ql[32];
#pragma unroll
        for (int i = 0; i < 8; ++i) {
            float4 qv = *(const float4*)(q + base + (long)row * (HH * DD) + p * 32 + 4 * i);
            ql[4 * i + 0] = qv.x * scale; ql[4 * i + 1] = qv.y * scale;
            ql[4 * i + 2] = qv.z * scale; ql[4 * i + 3] = qv.w * scale;
        }
        __syncthreads();

        // ---- s[row][j] for j = p + 4*jj ----
        float sL[16];
#pragma unroll
        for (int jj = 0; jj < 16; ++jj) sL[jj] = 0.f;
        for (int d4h = 0; d4h < 4; ++d4h) {
#pragma unroll
            for (int d4l = 0; d4l < 8; ++d4l) {
                float qd[4];
#pragma unroll
                for (int m = 0; m < 4; ++m)
                    qd[m] = __shfl(ql[4 * d4l + m], (lane & 60) | d4h, 64);
#pragma unroll
                for (int jj = 0; jj < 16; ++jj) {
                    int j = p + 4 * jj;
                    float4 kv = *(const float4*)(&lk[j][32 * d4h + 4 * d4l]);
                    sL[jj] += qd[0] * kv.x + qd[1] * kv.y + qd[2] * kv.z + qd[3] * kv.w;
                }
            }
        }
        // causal mask (inclusive)
#pragma unroll
        for (int jj = 0; jj < 16; ++jj)
            if (p + 4 * jj > row) sL[jj] = 0.f;

        // ---- o = s @ v + qs @ h ----
        float4 oa[8];
#pragma unroll
        for (int i = 0; i < 8; ++i) oa[i] = make_float4(0.f, 0.f, 0.f, 0.f);
        int jmax = (wave << 4) + 15;   // max row in this wave
        for (int j = 0; j <= jmax; ++j) {
            float sj = __shfl(sL[j >> 2], (lane & 60) | (j & 3), 64);
            const float4* vrow = (const float4*)(&lv[j][0]);
#pragma unroll
            for (int i = 0; i < 8; ++i) {
                float4 vx = vrow[p + 4 * i];
                oa[i].x += sj * vx.x; oa[i].y += sj * vx.y;
                oa[i].z += sj * vx.z; oa[i].w += sj * vx.w;
            }
        }
        for (int dh = 0; dh < 4; ++dh) {
#pragma unroll
            for (int dl = 0; dl < 32; ++dl) {
                float qd = __shfl(ql[dl], (lane & 60) | dh, 64);
                const float4* hrow = (const float4*)(&hS[32 * dh + dl][0]);
#pragma unroll
                for (int i = 0; i < 8; ++i) {
                    float4 hv = hrow[p + 4 * i];
                    oa[i].x += qd * hv.x; oa[i].y += qd * hv.y;
                    oa[i].z += qd * hv.z; oa[i].w += qd * hv.w;
                }
            }
        }
        float* orow = o + base + (long)row * (HH * DD);
#pragma unroll
        for (int i = 0; i < 8; ++i)
            *(float4*)(orow + 4 * (p + 4 * i)) = oa[i];

        __syncthreads();  // all h reads done before update

        // ---- h += k^T v ----
        {
            int d0  = t >> 1;
            int e4b = (t & 1) * 16;
            float4 ua[16];
#pragma unroll
            for (int i = 0; i < 16; ++i) ua[i] = make_float4(0.f, 0.f, 0.f, 0.f);
            for (int r = 0; r < CHUNK; ++r) {
                float kd = lk[r][d0];
                const float4* vrow = (const float4*)(&lv[r][0]);
#pragma unroll
                for (int i = 0; i < 16; ++i) {
                    float4 vx = vrow[e4b + i];
                    ua[i].x += kd * vx.x; ua[i].y += kd * vx.y;
                    ua[i].z += kd * vx.z; ua[i].w += kd * vx.w;
                }
            }
            float4* hrow = (float4*)(&hS[d0][0]);
#pragma unroll
            for (int i = 0; i < 16; ++i) {
                float4 cur = hrow[e4b + i];
                cur.x += ua[i].x; cur.y += ua[i].y;
                cur.z += ua[i].z; cur.w += ua[i].w;
                hrow[e4b + i] = cur;
            }
        }
    }
}

extern "C" void kernel_launch(void* const* d_in, const int* in_sizes, int n_in,
                              void* d_out, int out_size, void* d_ws, size_t ws_size,
                              hipStream_t stream) {
    const float* q = (const float*)d_in[0];
    const float* k = (const float*)d_in[1];
    const float* v = (const float*)d_in[2];
    float* o  = (float*)d_out;
    float* hf = o + (long)BB * SS * HH * DD;
    float* G  = (float*)d_ws;

    int NG = 16;
    while (NG > 1 && (size_t)BB * HH * NG * DD * DD * 4 > ws_size) NG >>= 1;
    int CPG = NTC / NG;
    float scale = 1.0f / sqrtf((float)DD);

    ksum_kernel<<<dim3(NG, HH, BB), 256, 0, stream>>>(k, v, G, CPG, NG);
    prefix_kernel<<<dim3(8, HH, BB), 256, 0, stream>>>(G, hf, NG);
    scan_kernel<<<dim3(NG, HH, BB), 256, 0, stream>>>(q, k, v, G, o, CPG, NG, scale);
}

// Round 2
// 107.503 us; speedup vs baseline: 5.9713x; 5.9713x over previous
//
#include <hip/hip_runtime.h>
#include <math.h>

#define BB 2
#define SS 4096
#define HH 16
#define DD 128
#define CK 64
#define NTC 64
#define HD 2048          // H*D row stride in elements
// LDS row strides in shorts (bf16). Both give word-stride == 4 (mod 32) -> even bank spread,
// and byte stride % 16 == 0 so b128 fragment loads stay 16B-aligned.
#define SQ 136           // rows of 128 (q, k, hT)
#define ST 72            // rows of 64  (kT, vT, S)

typedef __attribute__((ext_vector_type(8))) short bh8;     // 8 bf16 (4 VGPR)
typedef __attribute__((ext_vector_type(16))) float fx16;   // 32x32 accumulator

#define MFMA32(a, b, c) __builtin_amdgcn_mfma_f32_32x32x16_bf16(a, b, c, 0, 0, 0)

__device__ inline unsigned short f2bf(float f) {
    unsigned int u = __float_as_uint(f);
    return (unsigned short)((u + 0x7FFFu + ((u >> 16) & 1u)) >> 16);  // RNE
}
__device__ inline unsigned int pk2(float a, float b) {
    return (unsigned int)f2bf(a) | ((unsigned int)f2bf(b) << 16);
}

// ---------------- Phase 1: per-group sums of K^T V (MFMA) ----------------
// grid (NG, H, B), 512 threads. G stored as h[d][e] f32 (d-major).
__global__ __launch_bounds__(512, 4) void ksum_kernel(const float* __restrict__ k,
                                                      const float* __restrict__ v,
                                                      float* __restrict__ G,
                                                      int CPG, int NG) {
    int g = blockIdx.x, h = blockIdx.y, b = blockIdx.z;
    int t = threadIdx.x, l = t & 63, w = t >> 6, hi = l >> 5;
    __shared__ short lkT[128 * ST];
    __shared__ short lvT[128 * ST];
    int ebb = w >> 1, db0 = (w & 1) * 2;   // wave owns hT tiles (ebb, db0) (ebb, db0+1)
    fx16 h0 = {}, h1 = {};
    long hbase = ((long)b * SS) * HD + (long)h * DD;

    for (int c = 0; c < CPG; ++c) {
        long base = hbase + (long)(g * CPG + c) * CK * HD;
        // stage kT[d][c], vT[e][c] (bf16), conflict-free write mapping
        for (int i = 0; i < 8; ++i) {
            int it = t + 512 * i;
            int e  = (it & 15) + 16 * ((it >> 6) & 7);   // 0..127 (transposed row)
            int c2 = ((it >> 4) & 3) + 4 * (it >> 9);    // chunk-row pair 0..31
            long ga = base + (long)(2 * c2) * HD + e;
            *(unsigned int*)&lkT[e * ST + 2 * c2] = pk2(k[ga], k[ga + HD]);
            *(unsigned int*)&lvT[e * ST + 2 * c2] = pk2(v[ga], v[ga + HD]);
        }
        __syncthreads();
        // hT[e][d] += sum_c vT[e][c] * k[c][d]
#pragma unroll
        for (int ks = 0; ks < 4; ++ks) {
            bh8 A  = *(const bh8*)&lvT[(32 * ebb + (l & 31)) * ST + 16 * ks + 8 * hi];
            bh8 B0 = *(const bh8*)&lkT[(32 * db0 + (l & 31)) * ST + 16 * ks + 8 * hi];
            bh8 B1 = *(const bh8*)&lkT[(32 * db0 + 32 + (l & 31)) * ST + 16 * ks + 8 * hi];
            h0 = MFMA32(A, B0, h0);
            h1 = MFMA32(A, B1, h1);
        }
        __syncthreads();   // reads done before restage
    }
    // write G as h[d][e]: lane holds hT[e][d] -> store transposed via float4 packs
    float* Gp = G + ((long)(b * HH + h) * NG + g) * (DD * DD);
#pragma unroll
    for (int i = 0; i < 2; ++i) {
        int d = 32 * (db0 + i) + (l & 31);
#pragma unroll
        for (int q4 = 0; q4 < 4; ++q4) {
            float4 val;
            if (i == 0) val = make_float4(h0[4*q4], h0[4*q4+1], h0[4*q4+2], h0[4*q4+3]);
            else        val = make_float4(h1[4*q4], h1[4*q4+1], h1[4*q4+2], h1[4*q4+3]);
            *(float4*)&Gp[(long)d * DD + 32 * ebb + 8 * q4 + 4 * hi] = val;
        }
    }
}

// ---------------- Phase 2: exclusive prefix over groups (in-place) ----------------
// grid (8, H, B), block 256. Also writes final_state (total sum). G is h[d][e]; elementwise.
__global__ __launch_bounds__(256) void prefix_kernel(float* __restrict__ G,
                                                     float* __restrict__ hf,
                                                     int NG) {
    int eb = blockIdx.x * 16;
    int h = blockIdx.y, b = blockIdx.z;
    int t = threadIdx.x;
    int d0 = t >> 1;
    int eo = eb + (t & 1) * 8;
    long bh = (long)(b * HH + h);
    float4 a0 = make_float4(0.f, 0.f, 0.f, 0.f), a1 = a0;
    for (int g = 0; g < NG; ++g) {
        float* p = G + (bh * NG + g) * (DD * DD) + (long)d0 * DD + eo;
        float4 v0 = *(float4*)p;
        float4 v1 = *(float4*)(p + 4);
        *(float4*)p       = a0;
        *(float4*)(p + 4) = a1;
        a0.x += v0.x; a0.y += v0.y; a0.z += v0.z; a0.w += v0.w;
        a1.x += v1.x; a1.y += v1.y; a1.z += v1.z; a1.w += v1.w;
    }
    float* qp = hf + bh * (DD * DD) + (long)d0 * DD + eo;
    *(float4*)qp       = a0;
    *(float4*)(qp + 4) = a1;
}

// ---------------- Phase 3: per-group MFMA scan producing o ----------------
// grid (NG, H, B), 512 threads (8 waves). LDS ~116KB -> 1 block/CU.
__global__ __launch_bounds__(512, 2) void scan_kernel(const float* __restrict__ q,
                                                      const float* __restrict__ kk,
                                                      const float* __restrict__ vv,
                                                      const float* __restrict__ G,
                                                      float* __restrict__ o,
                                                      int CPG, int NG, float scale) {
    int g = blockIdx.x, h = blockIdx.y, b = blockIdx.z;
    int t = threadIdx.x, l = t & 63, w = t >> 6, hi = l >> 5;
    __shared__ short lq [64 * SQ];
    __shared__ short lk [64 * SQ];
    __shared__ short lS [64 * ST];
    __shared__ short lhT[128 * SQ];
    __shared__ short lkT[128 * ST];
    __shared__ short lvT[128 * ST];

    int ebb = w >> 1, db0 = (w & 1) * 2;   // m4/state tile ownership
    int rb = w >> 2, eb = w & 3;           // o tile ownership (32x32 at r0=32rb, e0=32eb)

    // init hT state regs from G (h[d][e] layout)
    fx16 h0 = {}, h1 = {};
    {
        const float* Gp = G + ((long)(b * HH + h) * NG + g) * (DD * DD);
#pragma unroll
        for (int i = 0; i < 2; ++i) {
            int d = 32 * (db0 + i) + (l & 31);
#pragma unroll
            for (int q4 = 0; q4 < 4; ++q4) {
                float4 val = *(const float4*)&Gp[(long)d * DD + 32 * ebb + 8 * q4 + 4 * hi];
                if (i == 0) { h0[4*q4] = val.x; h0[4*q4+1] = val.y; h0[4*q4+2] = val.z; h0[4*q4+3] = val.w; }
                else        { h1[4*q4] = val.x; h1[4*q4+1] = val.y; h1[4*q4+2] = val.z; h1[4*q4+3] = val.w; }
            }
        }
    }
    // initial bf16 mirror of hT into LDS
#pragma unroll
    for (int i = 0; i < 2; ++i) {
        int d = 32 * (db0 + i) + (l & 31);
#pragma unroll
        for (int rg = 0; rg < 16; ++rg) {
            int e = 32 * ebb + (rg & 3) + 8 * (rg >> 2) + 4 * hi;
            float x = (i == 0) ? h0[rg] : h1[rg];
            lhT[e * SQ + d] = (short)f2bf(x);
        }
    }

    long hbase = ((long)b * SS) * HD + (long)h * DD;
    for (int c = 0; c < CPG; ++c) {
        long base = hbase + (long)(g * CPG + c) * CK * HD;
        // (a) q (scaled), k row-major bf16
        for (int i = 0; i < 4; ++i) {
            int it = t + 512 * i;
            int r = it >> 5, d4 = it & 31;
            long ga = base + (long)r * HD + 4 * d4;
            float4 qv = *(const float4*)&q[ga];
            uint2 uq; uq.x = pk2(qv.x * scale, qv.y * scale); uq.y = pk2(qv.z * scale, qv.w * scale);
            *(uint2*)&lq[r * SQ + 4 * d4] = uq;
            float4 kv = *(const float4*)&kk[ga];
            uint2 uk; uk.x = pk2(kv.x, kv.y); uk.y = pk2(kv.z, kv.w);
            *(uint2*)&lk[r * SQ + 4 * d4] = uk;
        }
        // (b) transposed kT[d][c], vT[e][c]
        for (int i = 0; i < 8; ++i) {
            int it = t + 512 * i;
            int e  = (it & 15) + 16 * ((it >> 6) & 7);
            int c2 = ((it >> 4) & 3) + 4 * (it >> 9);
            long ga = base + (long)(2 * c2) * HD + e;
            *(unsigned int*)&lkT[e * ST + 2 * c2] = pk2(kk[ga], kk[ga + HD]);
            *(unsigned int*)&lvT[e * ST + 2 * c2] = pk2(vv[ga], vv[ga + HD]);
        }
        __syncthreads();   // staging + prev lhT writes visible

        // m1: S^T tiles on waves 0-3:  S^T[c][r] = sum_d k[c][d] * qs[r][d]
        if (w < 4) {
            int cb = w >> 1, rbs = w & 1;
            fx16 sa = {};
#pragma unroll
            for (int ks = 0; ks < 8; ++ks) {
                bh8 A = *(const bh8*)&lk[(32 * cb  + (l & 31)) * SQ + 16 * ks + 8 * hi];
                bh8 B = *(const bh8*)&lq[(32 * rbs + (l & 31)) * SQ + 16 * ks + 8 * hi];
                sa = MFMA32(A, B, sa);
            }
            // causal mask (keep c <= r), cvt, write S[r][c] row-major
            int r = 32 * rbs + (l & 31);
#pragma unroll
            for (int q4 = 0; q4 < 4; ++q4) {
                int cb4 = 32 * cb + 8 * q4 + 4 * hi;
                float x0 = (cb4 + 0 <= r) ? sa[4*q4+0] : 0.f;
                float x1 = (cb4 + 1 <= r) ? sa[4*q4+1] : 0.f;
                float x2 = (cb4 + 2 <= r) ? sa[4*q4+2] : 0.f;
                float x3 = (cb4 + 3 <= r) ? sa[4*q4+3] : 0.f;
                uint2 u; u.x = pk2(x0, x1); u.y = pk2(x2, x3);
                *(uint2*)&lS[r * ST + cb4] = u;
            }
        }
        __syncthreads();   // S visible

        // m2: o = S @ v   (A=S rows, B from vT)
        fx16 oa = {};
#pragma unroll
        for (int ks = 0; ks < 4; ++ks) {
            bh8 A = *(const bh8*)&lS [(32 * rb + (l & 31)) * ST + 16 * ks + 8 * hi];
            bh8 B = *(const bh8*)&lvT[(32 * eb + (l & 31)) * ST + 16 * ks + 8 * hi];
            oa = MFMA32(A, B, oa);
        }
        // m3: o += qs @ h  (B from hT mirror)
#pragma unroll
        for (int ks = 0; ks < 8; ++ks) {
            bh8 A = *(const bh8*)&lq [(32 * rb + (l & 31)) * SQ + 16 * ks + 8 * hi];
            bh8 B = *(const bh8*)&lhT[(32 * eb + (l & 31)) * SQ + 16 * ks + 8 * hi];
            oa = MFMA32(A, B, oa);
        }
        // write o (f32)
        {
            float* op = o + base;
            int e = 32 * eb + (l & 31);
#pragma unroll
            for (int rg = 0; rg < 16; ++rg) {
                int r = 32 * rb + (rg & 3) + 8 * (rg >> 2) + 4 * hi;
                op[(long)r * HD + e] = oa[rg];
            }
        }
        // m4: hT += v^T @ k (registers only)
#pragma unroll
        for (int ks = 0; ks < 4; ++ks) {
            bh8 A  = *(const bh8*)&lvT[(32 * ebb + (l & 31)) * ST + 16 * ks + 8 * hi];
            bh8 B0 = *(const bh8*)&lkT[(32 * db0 + (l & 31)) * ST + 16 * ks + 8 * hi];
            bh8 B1 = *(const bh8*)&lkT[(32 * db0 + 32 + (l & 31)) * ST + 16 * ks + 8 * hi];
            h0 = MFMA32(A, B0, h0);
            h1 = MFMA32(A, B1, h1);
        }
        __syncthreads();   // all lhT/lS/tile reads complete

        // refresh bf16 hT mirror for next chunk
#pragma unroll
        for (int i = 0; i < 2; ++i) {
            int d = 32 * (db0 + i) + (l & 31);
#pragma unroll
            for (int rg = 0; rg < 16; ++rg) {
                int e = 32 * ebb + (rg & 3) + 8 * (rg >> 2) + 4 * hi;
                float x = (i == 0) ? h0[rg] : h1[rg];
                lhT[e * SQ + d] = (short)f2bf(x);
            }
        }
    }
}

extern "C" void kernel_launch(void* const* d_in, const int* in_sizes, int n_in,
                              void* d_out, int out_size, void* d_ws, size_t ws_size,
                              hipStream_t stream) {
    const float* q = (const float*)d_in[0];
    const float* k = (const float*)d_in[1];
    const float* v = (const float*)d_in[2];
    float* o  = (float*)d_out;
    float* hf = o + (long)BB * SS * HH * DD;
    float* G  = (float*)d_ws;

    int NG = 16;
    while (NG > 1 && (size_t)BB * HH * NG * DD * DD * 4 > ws_size) NG >>= 1;
    int CPG = NTC / NG;
    float scale = 1.0f / sqrtf((float)DD);

    ksum_kernel<<<dim3(NG, HH, BB), 512, 0, stream>>>(k, v, G, CPG, NG);
    prefix_kernel<<<dim3(8, HH, BB), 256, 0, stream>>>(G, hf, NG);
    scan_kernel<<<dim3(NG, HH, BB), 512, 0, stream>>>(q, k, v, G, o, CPG, NG, scale);
}

// Round 3
// 91.458 us; speedup vs baseline: 7.0189x; 1.1754x over previous
//
#include <hip/hip_runtime.h>
#include <math.h>

#define BB 2
#define SS 4096
#define HH 16
#define DD 128
#define CK 64
#define NTC 64
#define HD 2048          // H*D row stride in elements
#define SQ 136           // LDS row stride (shorts) for rows of 128 (q, k, hT)
#define ST 72            // LDS row stride (shorts) for rows of 64  (kT, vT, S)

typedef __attribute__((ext_vector_type(8))) short bh8;     // 8 bf16 (4 VGPR)
typedef __attribute__((ext_vector_type(16))) float fx16;   // 32x32 accumulator

#define MFMA32(a, b, c) __builtin_amdgcn_mfma_f32_32x32x16_bf16(a, b, c, 0, 0, 0)

__device__ inline unsigned short f2bf(float f) {
    unsigned int u = __float_as_uint(f);
    return (unsigned short)((u + 0x7FFFu + ((u >> 16) & 1u)) >> 16);  // RNE
}
__device__ inline unsigned int pk2(float a, float b) {
    return (unsigned int)f2bf(a) | ((unsigned int)f2bf(b) << 16);
}

// ---------------- Phase 1: per-group sums of K^T V (MFMA, frag-ordered G) ----------------
// grid (NG, H, B), 512 threads.
__global__ __launch_bounds__(512, 2) void ksum_kernel(const float* __restrict__ k,
                                                      const float* __restrict__ v,
                                                      float* __restrict__ G,
                                                      int CPG, int NG) {
    int g = blockIdx.x, h = blockIdx.y, b = blockIdx.z;
    int t = threadIdx.x, l = t & 63, w = t >> 6, hi = l >> 5;
    __shared__ short lkT[128 * ST];
    __shared__ short lvT[128 * ST];
    int ebb = w >> 1, db0 = (w & 1) * 2;
    fx16 h0 = {}, h1 = {};
    long hbase = ((long)b * SS) * HD + (long)h * DD;

    float kt[16], vt[16];
#define KS_LOAD(cc)                                                              \
    {                                                                            \
        long base = hbase + (long)(g * CPG + (cc)) * CK * HD;                    \
        _Pragma("unroll") for (int i = 0; i < 8; ++i) {                          \
            int it = t + 512 * i;                                                \
            int e  = (it & 31) + 32 * (it >> 10);                                \
            int c2 = (it >> 5) & 31;                                             \
            long ga = base + (long)(2 * c2) * HD + e;                            \
            kt[2 * i] = k[ga]; kt[2 * i + 1] = k[ga + HD];                       \
            vt[2 * i] = v[ga]; vt[2 * i + 1] = v[ga + HD];                       \
        }                                                                        \
    }

    KS_LOAD(0);
    for (int c = 0; c < CPG; ++c) {
#pragma unroll
        for (int i = 0; i < 8; ++i) {
            int it = t + 512 * i;
            int e  = (it & 31) + 32 * (it >> 10);
            int c2 = (it >> 5) & 31;
            *(unsigned int*)&lkT[e * ST + 2 * c2] = pk2(kt[2 * i], kt[2 * i + 1]);
            *(unsigned int*)&lvT[e * ST + 2 * c2] = pk2(vt[2 * i], vt[2 * i + 1]);
        }
        __syncthreads();
        if (c + 1 < CPG) KS_LOAD(c + 1);
#pragma unroll
        for (int ks = 0; ks < 4; ++ks) {
            bh8 A  = *(const bh8*)&lvT[(32 * ebb + (l & 31)) * ST + 16 * ks + 8 * hi];
            bh8 B0 = *(const bh8*)&lkT[(32 * db0 + (l & 31)) * ST + 16 * ks + 8 * hi];
            bh8 B1 = *(const bh8*)&lkT[(32 * db0 + 32 + (l & 31)) * ST + 16 * ks + 8 * hi];
            h0 = MFMA32(A, B0, h0);
            h1 = MFMA32(A, B1, h1);
        }
        __syncthreads();
    }
    // fragment-ordered G write: fully coalesced
    float* Gp = G + ((long)(b * HH + h) * NG + g) * (DD * DD) + t * 32;
#pragma unroll
    for (int q4 = 0; q4 < 4; ++q4) {
        *(float4*)&Gp[4 * q4]      = make_float4(h0[4*q4], h0[4*q4+1], h0[4*q4+2], h0[4*q4+3]);
        *(float4*)&Gp[16 + 4 * q4] = make_float4(h1[4*q4], h1[4*q4+1], h1[4*q4+2], h1[4*q4+3]);
    }
}

// ---------------- Phase 2: exclusive prefix over groups (frag-ordered, in-place) --------
// grid 256 x 256 threads = 65536 = 32 bh * 2048; each thread owns 8 consecutive frag floats.
__global__ __launch_bounds__(256) void prefix_kernel(float* __restrict__ G,
                                                     float* __restrict__ hf,
                                                     int NG) {
    int tid = blockIdx.x * 256 + threadIdx.x;
    int bh = tid >> 11;
    int fl = (tid & 2047) * 8;          // local frag index 0..16383
    float* Gb = G + (long)bh * NG * (DD * DD) + fl;
    float4 a0 = make_float4(0.f, 0.f, 0.f, 0.f), a1 = a0;
    for (int g = 0; g < NG; ++g) {
        float* p = Gb + (long)g * (DD * DD);
        float4 v0 = *(float4*)p;
        float4 v1 = *(float4*)(p + 4);
        *(float4*)p       = a0;
        *(float4*)(p + 4) = a1;
        a0.x += v0.x; a0.y += v0.y; a0.z += v0.z; a0.w += v0.w;
        a1.x += v1.x; a1.y += v1.y; a1.z += v1.z; a1.w += v1.w;
    }
    // scatter total into semantic final_state hf[d][e]
    float acc[8] = {a0.x, a0.y, a0.z, a0.w, a1.x, a1.y, a1.z, a1.w};
    float* hb = hf + (long)bh * (DD * DD);
#pragma unroll
    for (int j = 0; j < 8; ++j) {
        int fi = fl + j;
        int w = fi >> 11, lv = (fi >> 5) & 63, i = (fi >> 4) & 1, rg = fi & 15;
        int d = 32 * ((w & 1) * 2 + i) + (lv & 31);
        int e = 32 * (w >> 1) + (rg & 3) + 8 * (rg >> 2) + 4 * (lv >> 5);
        hb[d * DD + e] = acc[j];
    }
}

// ---------------- Phase 3: per-group MFMA scan producing o ----------------
// grid (NG, H, B), 512 threads (8 waves). LDS ~113KB -> 1 block/CU.
__global__ __launch_bounds__(512, 2) void scan_kernel(const float* __restrict__ q,
                                                      const float* __restrict__ kk,
                                                      const float* __restrict__ vv,
                                                      const float* __restrict__ G,
                                                      float* __restrict__ o,
                                                      int CPG, int NG, float scale) {
    int g = blockIdx.x, h = blockIdx.y, b = blockIdx.z;
    int t = threadIdx.x, l = t & 63, w = t >> 6, hi = l >> 5;
    __shared__ short lq [64 * SQ];
    __shared__ short lk [64 * SQ];
    __shared__ short lS [64 * ST];
    __shared__ short lhT[128 * SQ];
    __shared__ short lkT[128 * ST];
    __shared__ short lvT[128 * ST];

    int ebb = w >> 1, db0 = (w & 1) * 2;   // state tile ownership
    int rb = w >> 2, eb = w & 3;           // o tile ownership

    // init hT state regs from fragment-ordered G (coalesced)
    fx16 h0 = {}, h1 = {};
    {
        const float* Gp = G + ((long)(b * HH + h) * NG + g) * (DD * DD) + t * 32;
#pragma unroll
        for (int q4 = 0; q4 < 4; ++q4) {
            float4 v0 = *(const float4*)&Gp[4 * q4];
            float4 v1 = *(const float4*)&Gp[16 + 4 * q4];
            h0[4*q4] = v0.x; h0[4*q4+1] = v0.y; h0[4*q4+2] = v0.z; h0[4*q4+3] = v0.w;
            h1[4*q4] = v1.x; h1[4*q4+1] = v1.y; h1[4*q4+2] = v1.z; h1[4*q4+3] = v1.w;
        }
    }
    // initial bf16 mirror of hT into LDS
#pragma unroll
    for (int i = 0; i < 2; ++i) {
        int d = 32 * (db0 + i) + (l & 31);
#pragma unroll
        for (int rg = 0; rg < 16; ++rg) {
            int e = 32 * ebb + (rg & 3) + 8 * (rg >> 2) + 4 * hi;
            float x = (i == 0) ? h0[rg] : h1[rg];
            lhT[e * SQ + d] = (short)f2bf(x);
        }
    }

    long hbase = ((long)b * SS) * HD + (long)h * DD;
    float4 qf[4], kf[4];
    float kt[16], vt[16];
#define SC_LOAD(cc)                                                              \
    {                                                                            \
        long base = hbase + (long)(g * CPG + (cc)) * CK * HD;                    \
        _Pragma("unroll") for (int i = 0; i < 4; ++i) {                          \
            int it = t + 512 * i;                                                \
            int r = it >> 5, d4 = it & 31;                                       \
            long ga = base + (long)r * HD + 4 * d4;                              \
            qf[i] = *(const float4*)&q[ga];                                      \
            kf[i] = *(const float4*)&kk[ga];                                     \
        }                                                                        \
        _Pragma("unroll") for (int i = 0; i < 8; ++i) {                          \
            int it = t + 512 * i;                                                \
            int e  = (it & 31) + 32 * (it >> 10);                                \
            int c2 = (it >> 5) & 31;                                             \
            long ga = base + (long)(2 * c2) * HD + e;                            \
            kt[2 * i] = kk[ga]; kt[2 * i + 1] = kk[ga + HD];                     \
            vt[2 * i] = vv[ga]; vt[2 * i + 1] = vv[ga + HD];                     \
        }                                                                        \
    }

    SC_LOAD(0);
    for (int c = 0; c < CPG; ++c) {
        long base = hbase + (long)(g * CPG + c) * CK * HD;
        // ---- stage regs -> LDS ----
#pragma unroll
        for (int i = 0; i < 4; ++i) {
            int it = t + 512 * i;
            int r = it >> 5, d4 = it & 31;
            uint2 uq; uq.x = pk2(qf[i].x * scale, qf[i].y * scale); uq.y = pk2(qf[i].z * scale, qf[i].w * scale);
            *(uint2*)&lq[r * SQ + 4 * d4] = uq;
            uint2 uk; uk.x = pk2(kf[i].x, kf[i].y); uk.y = pk2(kf[i].z, kf[i].w);
            *(uint2*)&lk[r * SQ + 4 * d4] = uk;
        }
#pragma unroll
        for (int i = 0; i < 8; ++i) {
            int it = t + 512 * i;
            int e  = (it & 31) + 32 * (it >> 10);
            int c2 = (it >> 5) & 31;
            *(unsigned int*)&lkT[e * ST + 2 * c2] = pk2(kt[2 * i], kt[2 * i + 1]);
            *(unsigned int*)&lvT[e * ST + 2 * c2] = pk2(vt[2 * i], vt[2 * i + 1]);
        }
        __syncthreads();   // B1: staging + prev lhT refresh visible

        if (c + 1 < CPG) SC_LOAD(c + 1);   // prefetch next chunk (hidden under compute)

        if (w >= 4) {
            // m4 (waves 4-7): hT += v^T @ k, overlapped with m1
#pragma unroll
            for (int ks = 0; ks < 4; ++ks) {
                bh8 A  = *(const bh8*)&lvT[(32 * ebb + (l & 31)) * ST + 16 * ks + 8 * hi];
                bh8 B0 = *(const bh8*)&lkT[(32 * db0 + (l & 31)) * ST + 16 * ks + 8 * hi];
                bh8 B1 = *(const bh8*)&lkT[(32 * db0 + 32 + (l & 31)) * ST + 16 * ks + 8 * hi];
                h0 = MFMA32(A, B0, h0);
                h1 = MFMA32(A, B1, h1);
            }
        } else {
            // m1: S^T = k . qs^T
            int cb = w >> 1, rbs = w & 1;
            fx16 sa = {};
#pragma unroll
            for (int ks = 0; ks < 8; ++ks) {
                bh8 A = *(const bh8*)&lk[(32 * cb  + (l & 31)) * SQ + 16 * ks + 8 * hi];
                bh8 B = *(const bh8*)&lq[(32 * rbs + (l & 31)) * SQ + 16 * ks + 8 * hi];
                sa = MFMA32(A, B, sa);
            }
            int r = 32 * rbs + (l & 31);
#pragma unroll
            for (int q4 = 0; q4 < 4; ++q4) {
                int cb4 = 32 * cb + 8 * q4 + 4 * hi;
                float x0 = (cb4 + 0 <= r) ? sa[4*q4+0] : 0.f;
                float x1 = (cb4 + 1 <= r) ? sa[4*q4+1] : 0.f;
                float x2 = (cb4 + 2 <= r) ? sa[4*q4+2] : 0.f;
                float x3 = (cb4 + 3 <= r) ? sa[4*q4+3] : 0.f;
                uint2 u; u.x = pk2(x0, x1); u.y = pk2(x2, x3);
                *(uint2*)&lS[r * ST + cb4] = u;
            }
        }
        __syncthreads();   // B2: S visible

        // m2: o = S @ v ; m3: o += qs @ h (all waves)
        fx16 oa = {};
#pragma unroll
        for (int ks = 0; ks < 4; ++ks) {
            bh8 A = *(const bh8*)&lS [(32 * rb + (l & 31)) * ST + 16 * ks + 8 * hi];
            bh8 B = *(const bh8*)&lvT[(32 * eb + (l & 31)) * ST + 16 * ks + 8 * hi];
            oa = MFMA32(A, B, oa);
        }
#pragma unroll
        for (int ks = 0; ks < 8; ++ks) {
            bh8 A = *(const bh8*)&lq [(32 * rb + (l & 31)) * SQ + 16 * ks + 8 * hi];
            bh8 B = *(const bh8*)&lhT[(32 * eb + (l & 31)) * SQ + 16 * ks + 8 * hi];
            oa = MFMA32(A, B, oa);
        }
        {
            float* op = o + base;
            int e = 32 * eb + (l & 31);
#pragma unroll
            for (int rg = 0; rg < 16; ++rg) {
                int r = 32 * rb + (rg & 3) + 8 * (rg >> 2) + 4 * hi;
                op[(long)r * HD + e] = oa[rg];
            }
        }
        if (w < 4) {
            // m4 (waves 0-3), after m3
#pragma unroll
            for (int ks = 0; ks < 4; ++ks) {
                bh8 A  = *(const bh8*)&lvT[(32 * ebb + (l & 31)) * ST + 16 * ks + 8 * hi];
                bh8 B0 = *(const bh8*)&lkT[(32 * db0 + (l & 31)) * ST + 16 * ks + 8 * hi];
                bh8 B1 = *(const bh8*)&lkT[(32 * db0 + 32 + (l & 31)) * ST + 16 * ks + 8 * hi];
                h0 = MFMA32(A, B0, h0);
                h1 = MFMA32(A, B1, h1);
            }
        }
        __syncthreads();   // B3: all LDS reads of this chunk complete

        // refresh bf16 hT mirror for next chunk (post-m4 state)
#pragma unroll
        for (int i = 0; i < 2; ++i) {
            int d = 32 * (db0 + i) + (l & 31);
#pragma unroll
            for (int rg = 0; rg < 16; ++rg) {
                int e = 32 * ebb + (rg & 3) + 8 * (rg >> 2) + 4 * hi;
                float x = (i == 0) ? h0[rg] : h1[rg];
                lhT[e * SQ + d] = (short)f2bf(x);
            }
        }
    }
}

extern "C" void kernel_launch(void* const* d_in, const int* in_sizes, int n_in,
                              void* d_out, int out_size, void* d_ws, size_t ws_size,
                              hipStream_t stream) {
    const float* q = (const float*)d_in[0];
    const float* k = (const float*)d_in[1];
    const float* v = (const float*)d_in[2];
    float* o  = (float*)d_out;
    float* hf = o + (long)BB * SS * HH * DD;
    float* G  = (float*)d_ws;

    int NG = 8;
    while (NG > 1 && (size_t)BB * HH * NG * DD * DD * 4 > ws_size) NG >>= 1;
    int CPG = NTC / NG;
    float scale = 1.0f / sqrtf((float)DD);

    ksum_kernel<<<dim3(NG, HH, BB), 512, 0, stream>>>(k, v, G, CPG, NG);
    prefix_kernel<<<dim3(256, 1, 1), 256, 0, stream>>>(G, hf, NG);
    scan_kernel<<<dim3(NG, HH, BB), 512, 0, stream>>>(q, k, v, G, o, CPG, NG, scale);
}